// Round 1
// baseline (207.815 us; speedup 1.0000x reference)
//
#include <hip/hip_runtime.h>
#include <hip/hip_bf16.h>

#define B_    1024
#define N_    128
#define FEAT_ 512
#define HID_  256

typedef __bf16 bf16x8 __attribute__((ext_vector_type(8)));
typedef float  f32x4  __attribute__((ext_vector_type(4)));

__device__ __forceinline__ unsigned int f2bf(float f) {
    unsigned int u = __float_as_uint(f);
    u += 0x7fffu + ((u >> 16) & 1u);   // round-to-nearest-even
    return u >> 16;
}
__device__ __forceinline__ unsigned int pack2(float a, float b) {
    return f2bf(a) | (f2bf(b) << 16);
}

union U16x8 { uint4 u; bf16x8 v; };

// ---------------- projection: xp = x @ W + b  (fp32) ----------------
__global__ __launch_bounds__(256) void proj_kernel(
    const float* __restrict__ x, const float* __restrict__ W,
    const float* __restrict__ bias, float* __restrict__ xp)
{
    const int h  = threadIdx.x;        // output col 0..255
    const int b0 = blockIdx.x * 8;     // 8 rows per block amortize W reads
    float acc[8];
    const float bb = bias[h];
    #pragma unroll
    for (int i = 0; i < 8; ++i) acc[i] = bb;
    for (int f = 0; f < FEAT_; ++f) {
        const float w = W[f * HID_ + h];           // coalesced, L2-resident
        #pragma unroll
        for (int i = 0; i < 8; ++i)
            acc[i] += x[(size_t)(b0 + i) * FEAT_ + f] * w;  // uniform s_loads
    }
    #pragma unroll
    for (int i = 0; i < 8; ++i)
        xp[(size_t)(b0 + i) * HID_ + h] = acc[i];
}

// ---------------- main: distmat[b,n] = sqrt(d^T M_n d + 1e-12) ----------------
// grid = (16 b-tiles of 64 rows, 128 n); 256 threads = 4 waves.
// Wave w: rows wr=(w&1)*32 .. +31, cols (within 64-col chunk) wcg=(w>>1)*32 .. +31.
// A-frags (D rows, bf16) live in registers for the whole block (16 x bf16x8 = 64 VGPR).
// M_n is symmetric, so global rows of M_n serve as the B operand (k-major) directly.
__global__ __launch_bounds__(256) void dist_kernel(
    const float* __restrict__ xp, const float* __restrict__ means,
    const float* __restrict__ invcov, float* __restrict__ out)
{
    constexpr int BT  = 64;
    constexpr int JC  = 64;
    constexpr int LDK = HID_ + 8;      // +8 bf16 pad -> uniform bank spread on b128 reads
    __shared__ unsigned short Ms[JC][LDK];     // 33792 B
    __shared__ float dist_acc[BT][2];

    const int tid  = threadIdx.x;
    const int n    = blockIdx.y;
    const int b0   = blockIdx.x * BT;
    const int wave = tid >> 6;
    const int lane = tid & 63;
    const int q    = lane >> 4;        // quad 0..3
    const int l    = lane & 15;
    const int wr   = (wave & 1) * 32;  // wave row offset in tile
    const int wcg  = wave >> 1;        // wave col group (0/1) -> cols wcg*32

    const float* mrow = means + (size_t)n * HID_;

    // ---- load A fragments into registers: D[b0+wr+rb*16+l][k], all K ----
    // A layout (verified m120): A[m=lane&15][k=quad*8+j]
    bf16x8 afrag[2][8];
    #pragma unroll
    for (int kk = 0; kk < 8; ++kk) {
        const int k0 = kk * 32 + q * 8;
        const float4 m0 = *(const float4*)(mrow + k0);
        const float4 m1 = *(const float4*)(mrow + k0 + 4);
        #pragma unroll
        for (int rb = 0; rb < 2; ++rb) {
            const float* xr = xp + (size_t)(b0 + wr + rb * 16 + l) * HID_;
            const float4 x0 = *(const float4*)(xr + k0);
            const float4 x1 = *(const float4*)(xr + k0 + 4);
            U16x8 c;
            c.u = make_uint4(pack2(x0.x - m0.x, x0.y - m0.y),
                             pack2(x0.z - m0.z, x0.w - m0.w),
                             pack2(x1.x - m1.x, x1.y - m1.y),
                             pack2(x1.z - m1.z, x1.w - m1.w));
            afrag[rb][kk] = c.v;
        }
    }

    float part[8] = {0.f,0.f,0.f,0.f,0.f,0.f,0.f,0.f};  // [rb*4+r] row partials

    for (int jc = 0; jc < HID_; jc += JC) {
        __syncthreads();   // previous chunk's LDS reads done before restage
        // ---- stage Ms[j][k] = bf16(invcov[n][jc+j][k]), 64 rows x 256 k ----
        #pragma unroll
        for (int t = 0; t < 8; ++t) {
            const int id  = tid + t * 256;    // 0..2047
            const int row = id >> 5;          // 0..63
            const int kc  = (id & 31) * 8;    // 0..248
            const float* src = invcov + ((size_t)n * HID_ + (jc + row)) * HID_ + kc;
            const float4 a = *(const float4*)src;
            const float4 b = *(const float4*)(src + 4);
            *(uint4*)&Ms[row][kc] = make_uint4(pack2(a.x, a.y), pack2(a.z, a.w),
                                               pack2(b.x, b.y), pack2(b.z, b.w));
        }
        __syncthreads();

        f32x4 acc00 = {0.f,0.f,0.f,0.f}, acc01 = {0.f,0.f,0.f,0.f};
        f32x4 acc10 = {0.f,0.f,0.f,0.f}, acc11 = {0.f,0.f,0.f,0.f};
        #pragma unroll
        for (int kk = 0; kk < 8; ++kk) {
            const int k0 = kk * 32 + q * 8;
            const bf16x8 bf0 = *(const bf16x8*)&Ms[wcg * 32 + l][k0];
            const bf16x8 bf1 = *(const bf16x8*)&Ms[wcg * 32 + 16 + l][k0];
            acc00 = __builtin_amdgcn_mfma_f32_16x16x32_bf16(afrag[0][kk], bf0, acc00, 0, 0, 0);
            acc01 = __builtin_amdgcn_mfma_f32_16x16x32_bf16(afrag[0][kk], bf1, acc01, 0, 0, 0);
            acc10 = __builtin_amdgcn_mfma_f32_16x16x32_bf16(afrag[1][kk], bf0, acc10, 0, 0, 0);
            acc11 = __builtin_amdgcn_mfma_f32_16x16x32_bf16(afrag[1][kk], bf1, acc11, 0, 0, 0);
        }

        // ---- fuse: part[rb*4+r] += sum_cb T[row][j_cb] * (xp[row][j]-mu[j]) fp32 ----
        // C/D layout (verified m89/m91): col=lane&15, row=quad*4+reg
        const int jA = jc + wcg * 32 + l;
        const int jB = jA + 16;
        const float muA = mrow[jA];
        const float muB = mrow[jB];
        #pragma unroll
        for (int rb = 0; rb < 2; ++rb) {
            #pragma unroll
            for (int r = 0; r < 4; ++r) {
                const int row = b0 + wr + rb * 16 + q * 4 + r;
                const float dA = xp[(size_t)row * HID_ + jA] - muA;
                const float dB = xp[(size_t)row * HID_ + jB] - muB;
                const f32x4 a0 = rb ? acc10 : acc00;
                const f32x4 a1 = rb ? acc11 : acc01;
                part[rb * 4 + r] += a0[r] * dA + a1[r] * dB;
            }
        }
    }

    // reduce each row-partial across the 16 col-lanes of its quad
    #pragma unroll
    for (int i = 0; i < 8; ++i) {
        float v = part[i];
        v += __shfl_xor(v, 1);
        v += __shfl_xor(v, 2);
        v += __shfl_xor(v, 4);
        v += __shfl_xor(v, 8);
        part[i] = v;
    }
    if (l == 0) {
        #pragma unroll
        for (int i = 0; i < 8; ++i) {
            const int row = wr + (i >> 2) * 16 + q * 4 + (i & 3);
            dist_acc[row][wcg] = part[i];
        }
    }
    __syncthreads();
    if (tid < BT) {
        const float s = dist_acc[tid][0] + dist_acc[tid][1];
        out[1 + (size_t)(b0 + tid) * N_ + n] = sqrtf(s + 1e-12f);
    }
}

// ---------------- loss: sum_b distmat[b, labels[b]] / B + clip residue ----------------
__global__ __launch_bounds__(256) void loss_kernel(
    const float* __restrict__ distmat, const int* __restrict__ labels,
    float* __restrict__ out)
{
    __shared__ float red[4];
    const int tid = threadIdx.x;
    float s = 0.f;
    for (int b = tid; b < B_; b += 256)
        s += distmat[(size_t)b * N_ + labels[b]];
    #pragma unroll
    for (int m = 32; m >= 1; m >>= 1) s += __shfl_down(s, m);
    if ((tid & 63) == 0) red[tid >> 6] = s;
    __syncthreads();
    if (tid == 0) {
        const float total = red[0] + red[1] + red[2] + red[3];
        // masked-out entries clip to 1e-12: B*(N-1) of them, /B -> (N-1)*1e-12
        out[0] = total / (float)B_ + (float)(N_ - 1) * 1e-12f;
    }
}

extern "C" void kernel_launch(void* const* d_in, const int* in_sizes, int n_in,
                              void* d_out, int out_size, void* d_ws, size_t ws_size,
                              hipStream_t stream) {
    const float* x      = (const float*)d_in[0];
    const int*   labels = (const int*)d_in[1];
    const float* W      = (const float*)d_in[2];
    const float* bias   = (const float*)d_in[3];
    const float* means  = (const float*)d_in[4];
    const float* invcov = (const float*)d_in[5];
    float* out = (float*)d_out;
    float* xp  = (float*)d_ws;   // B_*HID_ fp32 = 1 MB scratch

    proj_kernel<<<dim3(B_ / 8), 256, 0, stream>>>(x, W, bias, xp);
    dist_kernel<<<dim3(B_ / 64, N_), 256, 0, stream>>>(xp, means, invcov, out);
    loss_kernel<<<1, 256, 0, stream>>>(out + 1, labels, out);
}

// Round 2
// 164.648 us; speedup vs baseline: 1.2622x; 1.2622x over previous
//
#include <hip/hip_runtime.h>
#include <hip/hip_bf16.h>

#define B_    1024
#define N_    128
#define FEAT_ 512
#define HID_  256
#define LDK   264   // shorts per LDS row: 256 + 8 pad -> row stride 528B = 33 granules (odd) -> uniform bank spread

typedef __bf16 bf16x8 __attribute__((ext_vector_type(8)));
typedef float  f32x4  __attribute__((ext_vector_type(4)));

__device__ __forceinline__ unsigned int f2bf(float f) {
    unsigned int u = __float_as_uint(f);
    u += 0x7fffu + ((u >> 16) & 1u);   // round-to-nearest-even
    return u >> 16;
}
__device__ __forceinline__ unsigned int pack2(float a, float b) {
    return f2bf(a) | (f2bf(b) << 16);
}

union U16x8 { uint4 u; bf16x8 v; };

// ---------------- projection: xp = x @ W + b  (fp32) ----------------
// 256 blocks (1/CU), 4 rows/block; unrolled so 8 W-loads are in flight.
__global__ __launch_bounds__(256) void proj_kernel(
    const float* __restrict__ x, const float* __restrict__ W,
    const float* __restrict__ bias, float* __restrict__ xp)
{
    const int h  = threadIdx.x;        // output col 0..255
    const int b0 = blockIdx.x * 4;
    const float bb = bias[h];
    float a0 = bb, a1 = bb, a2 = bb, a3 = bb;
    const float* x0p = x + (size_t)(b0 + 0) * FEAT_;
    const float* x1p = x + (size_t)(b0 + 1) * FEAT_;
    const float* x2p = x + (size_t)(b0 + 2) * FEAT_;
    const float* x3p = x + (size_t)(b0 + 3) * FEAT_;
    #pragma unroll 2
    for (int f = 0; f < FEAT_; f += 4) {
        const float4 xv0 = *(const float4*)(x0p + f);   // uniform -> s_load_dwordx4
        const float4 xv1 = *(const float4*)(x1p + f);
        const float4 xv2 = *(const float4*)(x2p + f);
        const float4 xv3 = *(const float4*)(x3p + f);
        const float w0 = W[(size_t)(f + 0) * HID_ + h]; // coalesced, L2-resident
        const float w1 = W[(size_t)(f + 1) * HID_ + h];
        const float w2 = W[(size_t)(f + 2) * HID_ + h];
        const float w3 = W[(size_t)(f + 3) * HID_ + h];
        a0 += xv0.x * w0 + xv0.y * w1 + xv0.z * w2 + xv0.w * w3;
        a1 += xv1.x * w0 + xv1.y * w1 + xv1.z * w2 + xv1.w * w3;
        a2 += xv2.x * w0 + xv2.y * w1 + xv2.z * w2 + xv2.w * w3;
        a3 += xv3.x * w0 + xv3.y * w1 + xv3.z * w2 + xv3.w * w3;
    }
    xp[(size_t)(b0 + 0) * HID_ + h] = a0;
    xp[(size_t)(b0 + 1) * HID_ + h] = a1;
    xp[(size_t)(b0 + 2) * HID_ + h] = a2;
    xp[(size_t)(b0 + 3) * HID_ + h] = a3;
}

// ---------------- main: distmat[b,n] = sqrt(d^T M_n d + 1e-12) ----------------
// grid (2 row-halves, 128 n) = 256 blocks, 512 threads (8 waves), 135 KB dynamic LDS.
// Full M_n staged as bf16 into LDS ONCE (1 barrier); main loop is pure LDS+MFMA+
// fused epilogue, no barriers. Wave w owns rows w*64..w*64+63 (4 row-blocks of 16);
// afrag (bf16 delta, all K) resident in 128 VGPRs -> each B-frag LDS read feeds 4 MFMAs.
// M_n is symmetric, so M rows serve as the B operand (k-major) directly.
__global__ __launch_bounds__(512, 2) void dist_kernel(
    const float* __restrict__ xp, const float* __restrict__ means,
    const float* __restrict__ invcov, float* __restrict__ out)
{
    extern __shared__ unsigned short Ms[];   // [256][LDK] bf16 = 135168 B

    const int tid  = threadIdx.x;
    const int n    = blockIdx.y;
    const int b0   = blockIdx.x * 512;
    const int wave = tid >> 6;
    const int lane = tid & 63;
    const int q    = lane >> 4;        // quad 0..3
    const int l    = lane & 15;

    // ---- stage full M_n fp32 -> bf16 into LDS (once per block) ----
    const float* Msrc = invcov + (size_t)n * (HID_ * HID_);
    #pragma unroll
    for (int i = 0; i < 16; ++i) {
        const int g   = tid + i * 512;    // 16B-granule id 0..8191
        const int row = g >> 5;           // 0..255
        const int gc  = g & 31;           // granule within row
        const float* src = Msrc + (size_t)row * HID_ + gc * 8;
        const float4 a = *(const float4*)src;
        const float4 b = *(const float4*)(src + 4);
        *(uint4*)&Ms[row * LDK + gc * 8] =
            make_uint4(pack2(a.x, a.y), pack2(a.z, a.w), pack2(b.x, b.y), pack2(b.z, b.w));
    }

    // ---- afrag setup overlaps staging: delta rows (bf16), all K in registers ----
    // A layout (verified m120/R1): A[m=lane&15][k=quad*8+j]
    const float* mrow = means + (size_t)n * HID_;
    bf16x8 afrag[4][8];
    #pragma unroll
    for (int kk = 0; kk < 8; ++kk) {
        const int k0 = kk * 32 + q * 8;
        const float4 m0 = *(const float4*)(mrow + k0);
        const float4 m1 = *(const float4*)(mrow + k0 + 4);
        #pragma unroll
        for (int rb = 0; rb < 4; ++rb) {
            const float* xr = xp + (size_t)(b0 + wave * 64 + rb * 16 + l) * HID_;
            const float4 x0 = *(const float4*)(xr + k0);
            const float4 x1 = *(const float4*)(xr + k0 + 4);
            U16x8 c;
            c.u = make_uint4(pack2(x0.x - m0.x, x0.y - m0.y),
                             pack2(x0.z - m0.z, x0.w - m0.w),
                             pack2(x1.x - m1.x, x1.y - m1.y),
                             pack2(x1.z - m1.z, x1.w - m1.w));
            afrag[rb][kk] = c.v;
        }
    }
    __syncthreads();   // the ONLY barrier

    // precompute per-lane mu values for the fused epilogue (j = ct*16 + l)
    float muv[16];
    #pragma unroll
    for (int ct = 0; ct < 16; ++ct) muv[ct] = mrow[ct * 16 + l];

    float part[16];    // [rb*4+r] row partial sums of T .* delta
    #pragma unroll
    for (int i = 0; i < 16; ++i) part[i] = 0.f;

    const size_t xbase = (size_t)(b0 + wave * 64 + q * 4) * HID_ + l;  // row q*4, col l

    for (int ct = 0; ct < 16; ++ct) {
        f32x4 acc0 = {0.f,0.f,0.f,0.f}, acc1 = {0.f,0.f,0.f,0.f};
        f32x4 acc2 = {0.f,0.f,0.f,0.f}, acc3 = {0.f,0.f,0.f,0.f};
        #pragma unroll
        for (int kk = 0; kk < 8; ++kk) {
            const bf16x8 bfrag = *(const bf16x8*)&Ms[(ct * 16 + l) * LDK + kk * 32 + q * 8];
            acc0 = __builtin_amdgcn_mfma_f32_16x16x32_bf16(afrag[0][kk], bfrag, acc0, 0, 0, 0);
            acc1 = __builtin_amdgcn_mfma_f32_16x16x32_bf16(afrag[1][kk], bfrag, acc1, 0, 0, 0);
            acc2 = __builtin_amdgcn_mfma_f32_16x16x32_bf16(afrag[2][kk], bfrag, acc2, 0, 0, 0);
            acc3 = __builtin_amdgcn_mfma_f32_16x16x32_bf16(afrag[3][kk], bfrag, acc3, 0, 0, 0);
        }
        // fused epilogue: part[rb*4+r] += T[row][j] * delta_f32[row][j], j = ct*16+l
        // C/D layout (verified m89/m91/R1): col=lane&15, row=quad*4+reg
        const float mu = muv[ct];
        #pragma unroll
        for (int rb = 0; rb < 4; ++rb) {
            const f32x4 a = rb == 0 ? acc0 : rb == 1 ? acc1 : rb == 2 ? acc2 : acc3;
            #pragma unroll
            for (int r = 0; r < 4; ++r) {
                const float d = xp[xbase + (size_t)(rb * 16 + r) * HID_ + ct * 16] - mu;
                part[rb * 4 + r] += a[r] * d;
            }
        }
    }

    // reduce each row-partial across the 16 col-lanes of its quad
    #pragma unroll
    for (int i = 0; i < 16; ++i) {
        float v = part[i];
        v += __shfl_xor(v, 1);
        v += __shfl_xor(v, 2);
        v += __shfl_xor(v, 4);
        v += __shfl_xor(v, 8);
        part[i] = v;
    }
    if (l == 0) {
        #pragma unroll
        for (int i = 0; i < 16; ++i) {
            const int row = b0 + wave * 64 + (i >> 2) * 16 + q * 4 + (i & 3);
            out[1 + (size_t)row * N_ + n] = sqrtf(part[i] + 1e-12f);
        }
    }
}

// ---------------- loss: sum_b distmat[b, labels[b]] / B + clip residue ----------------
__global__ __launch_bounds__(1024) void loss_kernel(
    const float* __restrict__ distmat, const int* __restrict__ labels,
    float* __restrict__ out)
{
    __shared__ float red[16];
    const int b = threadIdx.x;                 // 1024 threads = one per batch row
    float s = distmat[(size_t)b * N_ + labels[b]];
    #pragma unroll
    for (int m = 1; m <= 32; m <<= 1) s += __shfl_xor(s, m);
    if ((b & 63) == 0) red[b >> 6] = s;
    __syncthreads();
    if (b == 0) {
        float t = 0.f;
        #pragma unroll
        for (int i = 0; i < 16; ++i) t += red[i];
        // masked-out entries clip to 1e-12: B*(N-1) of them, /B -> (N-1)*1e-12
        out[0] = t / (float)B_ + (float)(N_ - 1) * 1e-12f;
    }
}

extern "C" void kernel_launch(void* const* d_in, const int* in_sizes, int n_in,
                              void* d_out, int out_size, void* d_ws, size_t ws_size,
                              hipStream_t stream) {
    const float* x      = (const float*)d_in[0];
    const int*   labels = (const int*)d_in[1];
    const float* W      = (const float*)d_in[2];
    const float* bias   = (const float*)d_in[3];
    const float* means  = (const float*)d_in[4];
    const float* invcov = (const float*)d_in[5];
    float* out = (float*)d_out;
    float* xp  = (float*)d_ws;   // B_*HID_ fp32 = 1 MB scratch

    constexpr int DIST_LDS = 256 * LDK * 2;   // 135168 B dynamic LDS
    (void)hipFuncSetAttribute((const void*)dist_kernel,
                              hipFuncAttributeMaxDynamicSharedMemorySize, DIST_LDS);

    proj_kernel<<<dim3(B_ / 4), 256, 0, stream>>>(x, W, bias, xp);
    dist_kernel<<<dim3(2, N_), 512, DIST_LDS, stream>>>(xp, means, invcov, out);
    loss_kernel<<<1, 1024, 0, stream>>>(out + 1, labels, out);
}

// Round 3
// 163.345 us; speedup vs baseline: 1.2722x; 1.0080x over previous
//
#include <hip/hip_runtime.h>
#include <hip/hip_bf16.h>

#define B_    1024
#define N_    128
#define FEAT_ 512
#define HID_  256
#define LDK   264   // shorts per LDS row: 256 + 8 pad -> odd 16B-granule stride -> conflict-free b128

typedef __bf16 bf16x8 __attribute__((ext_vector_type(8)));
typedef float  f32x4  __attribute__((ext_vector_type(4)));

__device__ __forceinline__ unsigned int f2bf(float f) {
    unsigned int u = __float_as_uint(f);
    u += 0x7fffu + ((u >> 16) & 1u);   // round-to-nearest-even
    return u >> 16;
}
__device__ __forceinline__ unsigned int pack2(float a, float b) {
    return f2bf(a) | (f2bf(b) << 16);
}

union U16x8 { uint4 u; bf16x8 v; };

// ---------------- projection: xp = x @ W + b  (fp32) ----------------
// 512 blocks (2/CU), 2 rows/block, unroll 4 -> ~24 loads in flight.
__global__ __launch_bounds__(256) void proj_kernel(
    const float* __restrict__ x, const float* __restrict__ W,
    const float* __restrict__ bias, float* __restrict__ xp)
{
    const int h  = threadIdx.x;        // output col 0..255
    const int b0 = blockIdx.x * 2;
    const float bb = bias[h];
    float a0 = bb, a1 = bb;
    const float* x0p = x + (size_t)(b0 + 0) * FEAT_;
    const float* x1p = x + (size_t)(b0 + 1) * FEAT_;
    #pragma unroll 4
    for (int f = 0; f < FEAT_; f += 4) {
        const float4 xv0 = *(const float4*)(x0p + f);   // block-uniform -> s_load
        const float4 xv1 = *(const float4*)(x1p + f);
        const float w0 = W[(size_t)(f + 0) * HID_ + h]; // coalesced, L2-resident
        const float w1 = W[(size_t)(f + 1) * HID_ + h];
        const float w2 = W[(size_t)(f + 2) * HID_ + h];
        const float w3 = W[(size_t)(f + 3) * HID_ + h];
        a0 += xv0.x * w0 + xv0.y * w1 + xv0.z * w2 + xv0.w * w3;
        a1 += xv1.x * w0 + xv1.y * w1 + xv1.z * w2 + xv1.w * w3;
    }
    xp[(size_t)(b0 + 0) * HID_ + h] = a0;
    xp[(size_t)(b0 + 1) * HID_ + h] = a1;
}

// ---------------- main: p[jh][b][n] = sum_{j in half jh} T[b,j]*delta[b,j] ----------------
// grid (4 b-splits, 2 j-halves, 128 n) = 1024 blocks, 512 threads, 67.6 KB LDS
// -> 2 blocks/CU, target 4 waves/SIMD (regs <= 128: afrag 64 AGPR + ~60 VGPR).
// Block stages 128 rows of M_n (its j-half) as bf16 once; waves own 32 b-rows,
// afrag (bf16 delta, full K) resident; per 16-col tile: 16 MFMA fed by 8 ds_read_b128,
// then fused T*delta_f32 epilogue (loads hoisted ahead of the MFMA burst).
__global__ __launch_bounds__(512, 4) void dist_kernel(
    const float* __restrict__ xp, const float* __restrict__ means,
    const float* __restrict__ invcov, float* __restrict__ p)
{
    extern __shared__ unsigned short Ms[];   // [128][LDK] bf16 = 67584 B

    const int tid  = threadIdx.x;
    const int bh   = blockIdx.x;       // 0..3
    const int jh   = blockIdx.y;       // 0..1
    const int n    = blockIdx.z;       // 0..127
    const int b0   = bh * 256;
    const int wave = tid >> 6;
    const int lane = tid & 63;
    const int q    = lane >> 4;        // quad 0..3
    const int l    = lane & 15;

    // ---- stage M_n rows [jh*128, jh*128+128) fp32 -> bf16 into LDS ----
    const float* Msrc = invcov + (size_t)n * (HID_ * HID_) + (size_t)jh * 128 * HID_;
    #pragma unroll
    for (int i = 0; i < 8; ++i) {
        const int g   = tid + i * 512;    // 16B-granule id 0..4095
        const int row = g >> 5;           // 0..127
        const int gc  = g & 31;           // granule within row
        const float* src = Msrc + (size_t)row * HID_ + gc * 8;
        const float4 a = *(const float4*)src;
        const float4 b = *(const float4*)(src + 4);
        *(uint4*)&Ms[row * LDK + gc * 8] =
            make_uint4(pack2(a.x, a.y), pack2(a.z, a.w), pack2(b.x, b.y), pack2(b.z, b.w));
    }

    // ---- afrag setup (overlaps staging): delta rows (bf16), full K, 2 row-blocks ----
    // A layout: A[m=lane&15][k=quad*8+j]
    const float* mrow = means + (size_t)n * HID_;
    bf16x8 afrag[2][8];
    #pragma unroll
    for (int kk = 0; kk < 8; ++kk) {
        const int k0 = kk * 32 + q * 8;
        const float4 m0 = *(const float4*)(mrow + k0);
        const float4 m1 = *(const float4*)(mrow + k0 + 4);
        #pragma unroll
        for (int rb = 0; rb < 2; ++rb) {
            const float* xr = xp + (size_t)(b0 + wave * 32 + rb * 16 + l) * HID_;
            const float4 x0 = *(const float4*)(xr + k0);
            const float4 x1 = *(const float4*)(xr + k0 + 4);
            U16x8 c;
            c.u = make_uint4(pack2(x0.x - m0.x, x0.y - m0.y),
                             pack2(x0.z - m0.z, x0.w - m0.w),
                             pack2(x1.x - m1.x, x1.y - m1.y),
                             pack2(x1.z - m1.z, x1.w - m1.w));
            afrag[rb][kk] = c.v;
        }
    }

    // per-lane mu for the fused epilogue (j = jh*128 + ct*16 + l)
    float muv[8];
    #pragma unroll
    for (int ct = 0; ct < 8; ++ct) muv[ct] = mrow[jh * 128 + ct * 16 + l];

    __syncthreads();   // the ONLY barrier

    float part[8];     // [rb*4+r] row partials
    #pragma unroll
    for (int i = 0; i < 8; ++i) part[i] = 0.f;

    // epilogue base: row (b0 + wave*32 + q*4), col (jh*128 + l)
    const size_t xbase = (size_t)(b0 + wave * 32 + q * 4) * HID_ + jh * 128 + l;

    #pragma unroll
    for (int ct = 0; ct < 8; ++ct) {
        // hoist delta loads ahead of the MFMA burst
        float xl[8];
        #pragma unroll
        for (int rb = 0; rb < 2; ++rb)
            #pragma unroll
            for (int r = 0; r < 4; ++r)
                xl[rb * 4 + r] = xp[xbase + (size_t)(rb * 16 + r) * HID_ + ct * 16];

        f32x4 acc0 = {0.f,0.f,0.f,0.f}, acc1 = {0.f,0.f,0.f,0.f};
        #pragma unroll
        for (int kk = 0; kk < 8; ++kk) {
            const bf16x8 bfrag = *(const bf16x8*)&Ms[(ct * 16 + l) * LDK + kk * 32 + q * 8];
            acc0 = __builtin_amdgcn_mfma_f32_16x16x32_bf16(afrag[0][kk], bfrag, acc0, 0, 0, 0);
            acc1 = __builtin_amdgcn_mfma_f32_16x16x32_bf16(afrag[1][kk], bfrag, acc1, 0, 0, 0);
        }
        // fused epilogue: part += T[row][j] * delta_f32[row][j]
        // C/D layout: col=lane&15, row=quad*4+reg
        const float mu = muv[ct];
        #pragma unroll
        for (int r = 0; r < 4; ++r) {
            part[r]     += acc0[r] * (xl[r]     - mu);
            part[4 + r] += acc1[r] * (xl[4 + r] - mu);
        }
    }

    // reduce each row-partial across the 16 col-lanes of its quad
    #pragma unroll
    for (int i = 0; i < 8; ++i) {
        float v = part[i];
        v += __shfl_xor(v, 1);
        v += __shfl_xor(v, 2);
        v += __shfl_xor(v, 4);
        v += __shfl_xor(v, 8);
        part[i] = v;
    }
    if (l == 0) {
        float* pb = p + (size_t)jh * (B_ * N_);
        #pragma unroll
        for (int i = 0; i < 8; ++i) {
            const int row = b0 + wave * 32 + (i >> 2) * 16 + q * 4 + (i & 3);
            pb[(size_t)row * N_ + n] = part[i];
        }
    }
}

// ---------------- finalize: distmat = sqrt(p0 + p1 + 1e-12) ----------------
__global__ __launch_bounds__(256) void finalize_kernel(
    const float* __restrict__ p, float* __restrict__ out)
{
    const int i = blockIdx.x * 256 + threadIdx.x;   // 0..131071
    out[1 + i] = sqrtf(p[i] + p[B_ * N_ + i] + 1e-12f);
}

// ---------------- loss: sum_b distmat[b, labels[b]] / B + clip residue ----------------
__global__ __launch_bounds__(1024) void loss_kernel(
    const float* __restrict__ distmat, const int* __restrict__ labels,
    float* __restrict__ out)
{
    __shared__ float red[16];
    const int b = threadIdx.x;                 // 1024 threads = one per batch row
    float s = distmat[(size_t)b * N_ + labels[b]];
    #pragma unroll
    for (int m = 1; m <= 32; m <<= 1) s += __shfl_xor(s, m);
    if ((b & 63) == 0) red[b >> 6] = s;
    __syncthreads();
    if (b == 0) {
        float t = 0.f;
        #pragma unroll
        for (int i = 0; i < 16; ++i) t += red[i];
        // masked-out entries clip to 1e-12: B*(N-1) of them, /B -> (N-1)*1e-12
        out[0] = t / (float)B_ + (float)(N_ - 1) * 1e-12f;
    }
}

extern "C" void kernel_launch(void* const* d_in, const int* in_sizes, int n_in,
                              void* d_out, int out_size, void* d_ws, size_t ws_size,
                              hipStream_t stream) {
    const float* x      = (const float*)d_in[0];
    const int*   labels = (const int*)d_in[1];
    const float* W      = (const float*)d_in[2];
    const float* bias   = (const float*)d_in[3];
    const float* means  = (const float*)d_in[4];
    const float* invcov = (const float*)d_in[5];
    float* out = (float*)d_out;
    float* xp  = (float*)d_ws;                  // B_*HID_ fp32 = 1 MB
    float* p   = xp + (size_t)B_ * HID_;        // 2 x B_*N_ fp32 partials = 1 MB

    constexpr int DIST_LDS = 128 * LDK * 2;     // 67584 B dynamic LDS
    (void)hipFuncSetAttribute((const void*)dist_kernel,
                              hipFuncAttributeMaxDynamicSharedMemorySize, DIST_LDS);

    proj_kernel<<<dim3(B_ / 2), 256, 0, stream>>>(x, W, bias, xp);
    dist_kernel<<<dim3(4, 2, N_), 512, DIST_LDS, stream>>>(xp, means, invcov, p);
    finalize_kernel<<<dim3((B_ * N_) / 256), 256, 0, stream>>>(p, out);
    loss_kernel<<<1, 1024, 0, stream>>>(out + 1, labels, out);
}

// Round 4
// 159.758 us; speedup vs baseline: 1.3008x; 1.0225x over previous
//
#include <hip/hip_runtime.h>
#include <hip/hip_bf16.h>

#define B_    1024
#define N_    128
#define FEAT_ 512
#define HID_  256

typedef __bf16 bf16x8 __attribute__((ext_vector_type(8)));
typedef float  f32x4  __attribute__((ext_vector_type(4)));

__device__ __forceinline__ unsigned int f2bf(float f) {
    unsigned int u = __float_as_uint(f);
    u += 0x7fffu + ((u >> 16) & 1u);   // round-to-nearest-even
    return u >> 16;
}

// ---------------- prep: fused conv(M->bf16 swizzled, v2, cpart) + proj ----------------
// blocks [0,256): conv role, block=(n, k-half), 512 threads=(jj 0..3, k' 0..127).
//   Streams M_n fp32 once: accumulates v_k = sum_j mu_j M[j,k], writes bf16 M in the
//   granule-swizzled layout  elem(j,k) -> j*256 + ((k>>3)^((j&7)<<2))*8 + (k&7)
//   so dist's global_load_lds DMA image is bank-conflict-free (2-way max) for b128 reads.
// blocks [256,512): proj role, 4 rows/block, writes xp fp32 + xbf bf16.
__global__ __launch_bounds__(512) void prep_kernel(
    const float* __restrict__ x, const float* __restrict__ W,
    const float* __restrict__ bias, const float* __restrict__ means,
    const float* __restrict__ invcov,
    float* __restrict__ xp, unsigned short* __restrict__ xbf,
    unsigned short* __restrict__ Mbf, float* __restrict__ v2,
    float* __restrict__ cpart)
{
    __shared__ float sv[4][128];
    __shared__ float sw[2];
    const int t = threadIdx.x;
    if (blockIdx.x < 256) {
        const int n  = blockIdx.x >> 1;
        const int kh = blockIdx.x & 1;
        const int jj = t >> 7;            // 0..3, wave-uniform
        const int kp = t & 127;
        const int k  = kh * 128 + kp;
        const float* Mn = invcov + (size_t)n * (HID_ * HID_);
        const float* mu = means + (size_t)n * HID_;
        unsigned short* Mb = Mbf + (size_t)n * (HID_ * HID_);
        float v = 0.f;
        #pragma unroll 8
        for (int j0 = 0; j0 < HID_; j0 += 4) {
            const int j = j0 + jj;
            const float m = Mn[(size_t)j * HID_ + k];
            v += mu[j] * m;               // mu[j] wave-uniform -> s_load
            const int g2 = (k >> 3) ^ ((j & 7) << 2);
            Mb[(size_t)j * HID_ + g2 * 8 + (k & 7)] = (unsigned short)f2bf(m);
        }
        sv[jj][kp] = v;
        __syncthreads();
        if (t < 128) {
            const float vk = sv[0][t] + sv[1][t] + sv[2][t] + sv[3][t];
            v2[(size_t)n * HID_ + kh * 128 + t] = 2.f * vk;
            float cc = vk * mu[kh * 128 + t];
            cc += __shfl_xor(cc, 1);
            cc += __shfl_xor(cc, 2);
            cc += __shfl_xor(cc, 4);
            cc += __shfl_xor(cc, 8);
            cc += __shfl_xor(cc, 16);
            cc += __shfl_xor(cc, 32);
            if ((t & 63) == 0) sw[t >> 6] = cc;
        }
        __syncthreads();
        if (t == 0) cpart[n * 2 + kh] = sw[0] + sw[1];
    } else {
        const int b0 = (blockIdx.x - 256) * 4;
        const int h  = t & 255;
        const int rr = t >> 8;            // 0..1, wave-uniform
        const float bb = bias[h];
        float a0 = bb, a1 = bb;
        const float* x0p = x + (size_t)(b0 + rr * 2 + 0) * FEAT_;
        const float* x1p = x + (size_t)(b0 + rr * 2 + 1) * FEAT_;
        #pragma unroll 4
        for (int f = 0; f < FEAT_; f += 4) {
            const float4 xv0 = *(const float4*)(x0p + f);   // wave-uniform -> s_load
            const float4 xv1 = *(const float4*)(x1p + f);
            const float w0 = W[(size_t)(f + 0) * HID_ + h]; // coalesced, L2-resident
            const float w1 = W[(size_t)(f + 1) * HID_ + h];
            const float w2 = W[(size_t)(f + 2) * HID_ + h];
            const float w3 = W[(size_t)(f + 3) * HID_ + h];
            a0 += xv0.x * w0 + xv0.y * w1 + xv0.z * w2 + xv0.w * w3;
            a1 += xv1.x * w0 + xv1.y * w1 + xv1.z * w2 + xv1.w * w3;
        }
        const int r0 = b0 + rr * 2;
        xp [(size_t)(r0 + 0) * HID_ + h] = a0;
        xp [(size_t)(r0 + 1) * HID_ + h] = a1;
        xbf[(size_t)(r0 + 0) * HID_ + h] = (unsigned short)f2bf(a0);
        xbf[(size_t)(r0 + 1) * HID_ + h] = (unsigned short)f2bf(a1);
    }
}

// ---------------- dist: p[jh][b][n] = sum_{j in half} (T[b,j] - v2[n,j]) * xp[b,j] ----------------
// T = x . M_n (bf16 MFMA, fp32 acc). grid (4 bg, 2 jh, 128 n) = 1024 blocks,
// 512 threads, 64 KB LDS -> 2 blocks/CU. M-half staged by pure global_load_lds DMA
// (pre-converted, pre-swizzled bf16) — zero staging VALU. Wave owns 32 b-rows; afrag
// (x rows, bf16, full K) resident in 64 regs; per ct: 8 ds_read_b128 (2-way only) + 16 MFMA.
__global__ __launch_bounds__(512, 4) void dist_kernel(
    const float* __restrict__ xp, const unsigned short* __restrict__ xbf,
    const unsigned short* __restrict__ Mbf, const float* __restrict__ v2,
    float* __restrict__ p)
{
    extern __shared__ unsigned short Ms[];   // 128 rows x 256 el (swizzled) = 65536 B

    const int tid  = threadIdx.x;
    const int bh   = blockIdx.x;       // 0..3
    const int jh   = blockIdx.y;       // 0..1
    const int n    = blockIdx.z;       // 0..127
    const int wave = tid >> 6;
    const int lane = tid & 63;
    const int q    = lane >> 4;        // quad 0..3
    const int l    = lane & 15;

    // ---- DMA stage 64 KB M-half: 64 chunks of 1 KB (wave, iter) ----
    const unsigned short* src = Mbf + (size_t)n * (HID_ * HID_) + (size_t)jh * 32768;
    #pragma unroll
    for (int i = 0; i < 8; ++i) {
        const int c = i * 8 + wave;    // chunk id, wave-uniform
        __builtin_amdgcn_global_load_lds(
            (const __attribute__((address_space(1))) unsigned int*)(src + (size_t)c * 512 + lane * 8),
            (__attribute__((address_space(3))) unsigned int*)&Ms[c * 512],
            16, 0, 0);
    }

    // ---- afrag: x rows (bf16, pre-converted), full K, 2 row-blocks of 16 ----
    // A layout: A[m=lane&15][k=quad*8+j]
    bf16x8 afrag[2][8];
    #pragma unroll
    for (int rb = 0; rb < 2; ++rb) {
        const unsigned short* xr = xbf + (size_t)(bh * 256 + wave * 32 + rb * 16 + l) * HID_;
        #pragma unroll
        for (int kk = 0; kk < 8; ++kk)
            afrag[rb][kk] = *(const bf16x8*)(xr + kk * 32 + q * 8);
    }
    // v2 per lane per ct (j = jh*128 + ct*16 + l)
    float v2l[8];
    #pragma unroll
    for (int ct = 0; ct < 8; ++ct)
        v2l[ct] = v2[(size_t)n * HID_ + jh * 128 + ct * 16 + l];

    __syncthreads();   // drains the DMA (vmcnt) + the only barrier

    float part[8];
    #pragma unroll
    for (int i = 0; i < 8; ++i) part[i] = 0.f;

    // epilogue x source: row (bh*256 + wave*32 + q*4 + r + rb*16), col (jh*128 + ct*16 + l)
    const size_t xbase = (size_t)(bh * 256 + wave * 32 + q * 4) * HID_ + jh * 128 + l;

    #pragma unroll
    for (int ct = 0; ct < 8; ++ct) {
        // hoist fp32 x loads for the fused epilogue
        float xl[8];
        #pragma unroll
        for (int rb = 0; rb < 2; ++rb)
            #pragma unroll
            for (int r = 0; r < 4; ++r)
                xl[rb * 4 + r] = xp[xbase + (size_t)(rb * 16 + r) * HID_ + ct * 16];

        f32x4 acc0 = {0.f,0.f,0.f,0.f}, acc1 = {0.f,0.f,0.f,0.f};
        #pragma unroll
        for (int kk = 0; kk < 8; ++kk) {
            // swizzled read: row jr=ct*16+l, granule (kk*4+q)^((l&7)<<2)  -> 2-way banks (free)
            const bf16x8 bfrag = *(const bf16x8*)&Ms[(ct * 16 + l) * HID_ +
                                                     (((kk * 4 + q) ^ ((l & 7) << 2)) << 3)];
            acc0 = __builtin_amdgcn_mfma_f32_16x16x32_bf16(afrag[0][kk], bfrag, acc0, 0, 0, 0);
            acc1 = __builtin_amdgcn_mfma_f32_16x16x32_bf16(afrag[1][kk], bfrag, acc1, 0, 0, 0);
        }
        // fused epilogue: part += (T - v2) * x   (C/D layout: col=lane&15, row=quad*4+reg)
        const float vv = v2l[ct];
        #pragma unroll
        for (int r = 0; r < 4; ++r) {
            part[r]     += (acc0[r] - vv) * xl[r];
            part[4 + r] += (acc1[r] - vv) * xl[4 + r];
        }
    }

    // reduce across the 16 col-lanes of each quad
    #pragma unroll
    for (int i = 0; i < 8; ++i) {
        float v = part[i];
        v += __shfl_xor(v, 1);
        v += __shfl_xor(v, 2);
        v += __shfl_xor(v, 4);
        v += __shfl_xor(v, 8);
        part[i] = v;
    }
    if (l == 0) {
        float* pb = p + (size_t)jh * (B_ * N_);
        #pragma unroll
        for (int i = 0; i < 8; ++i) {
            const int row = bh * 256 + wave * 32 + (i >> 2) * 16 + q * 4 + (i & 3);
            pb[(size_t)row * N_ + n] = part[i];
        }
    }
}

// ---------------- finalize: distmat = sqrt(p0 + p1 + c[n] + 1e-12) ----------------
__global__ __launch_bounds__(256) void finalize_kernel(
    const float* __restrict__ p, const float* __restrict__ cpart,
    float* __restrict__ out)
{
    const int i = blockIdx.x * 256 + threadIdx.x;   // 0..131071
    const int n = i & (N_ - 1);
    const float c = cpart[n * 2] + cpart[n * 2 + 1];
    out[1 + i] = sqrtf(p[i] + p[B_ * N_ + i] + c + 1e-12f);
}

// ---------------- loss: sum_b distmat[b, labels[b]] / B + clip residue ----------------
__global__ __launch_bounds__(1024) void loss_kernel(
    const float* __restrict__ distmat, const int* __restrict__ labels,
    float* __restrict__ out)
{
    __shared__ float red[16];
    const int b = threadIdx.x;                 // 1024 threads = one per batch row
    float s = distmat[(size_t)b * N_ + labels[b]];
    #pragma unroll
    for (int m = 1; m <= 32; m <<= 1) s += __shfl_xor(s, m);
    if ((b & 63) == 0) red[b >> 6] = s;
    __syncthreads();
    if (b == 0) {
        float t = 0.f;
        #pragma unroll
        for (int i = 0; i < 16; ++i) t += red[i];
        // masked-out entries clip to 1e-12: B*(N-1) of them, /B -> (N-1)*1e-12
        out[0] = t / (float)B_ + (float)(N_ - 1) * 1e-12f;
    }
}

extern "C" void kernel_launch(void* const* d_in, const int* in_sizes, int n_in,
                              void* d_out, int out_size, void* d_ws, size_t ws_size,
                              hipStream_t stream) {
    const float* x      = (const float*)d_in[0];
    const int*   labels = (const int*)d_in[1];
    const float* W      = (const float*)d_in[2];
    const float* bias   = (const float*)d_in[3];
    const float* means  = (const float*)d_in[4];
    const float* invcov = (const float*)d_in[5];
    float* out = (float*)d_out;

    // workspace carve-up (19.53 MB total)
    char* ws = (char*)d_ws;
    unsigned short* Mbf   = (unsigned short*)(ws);               // 16,777,216 B
    float*          xp    = (float*)         (ws + 16777216);    //  1,048,576 B
    unsigned short* xbf   = (unsigned short*)(ws + 17825792);    //    524,288 B
    float*          v2    = (float*)         (ws + 18350080);    //    131,072 B
    float*          cpart = (float*)         (ws + 18481152);    //      1,024 B
    float*          p     = (float*)         (ws + 18482176);    //  1,048,576 B

    constexpr int DIST_LDS = 128 * HID_ * 2;   // 65536 B dynamic LDS
    (void)hipFuncSetAttribute((const void*)dist_kernel,
                              hipFuncAttributeMaxDynamicSharedMemorySize, DIST_LDS);

    prep_kernel<<<dim3(512), 512, 0, stream>>>(x, W, bias, means, invcov,
                                               xp, xbf, Mbf, v2, cpart);
    dist_kernel<<<dim3(4, 2, N_), 512, DIST_LDS, stream>>>(xp, xbf, Mbf, v2, p);
    finalize_kernel<<<dim3((B_ * N_) / 256), 256, 0, stream>>>(p, cpart, out);
    loss_kernel<<<1, 1024, 0, stream>>>(out + 1, labels, out);
}

// Round 5
// 147.855 us; speedup vs baseline: 1.4055x; 1.0805x over previous
//
#include <hip/hip_runtime.h>
#include <hip/hip_bf16.h>

#define B_    1024
#define N_    128
#define FEAT_ 512
#define HID_  256

typedef __bf16 bf16x8 __attribute__((ext_vector_type(8)));
typedef float  f32x4  __attribute__((ext_vector_type(4)));

__device__ __forceinline__ unsigned int f2bf(float f) {
    unsigned int u = __float_as_uint(f);
    u += 0x7fffu + ((u >> 16) & 1u);   // round-to-nearest-even
    return u >> 16;
}
__device__ __forceinline__ unsigned int pack2(float a, float b) {
    return f2bf(a) | (f2bf(b) << 16);
}

// ---------------- prep: fused conv(M->bf16 swizzled, v2, cpart) + proj ----------------
// blocks [0,512): conv role, block=(n, jq 0..3) covering 64 rows of M_n.
//   Thread owns one 16B granule per iter: 32B contiguous fp32 load -> uint4 store at
//   swizzled granule  elem(j,k) -> j*256 + ((k>>3)^((j&7)<<2))*8 + (k&7)
//   (wave = 2KB contiguous read, two permuted-but-covered 512B write windows).
//   v2[j] = 2*sum_k mu_k M[j,k] via LDS sv[64][33]; cpart = quarter-sum of mu_j v_j.
// blocks [512,768): proj role, 4 rows/block, writes xp fp32 + xbf bf16.
__global__ __launch_bounds__(256) void prep_kernel(
    const float* __restrict__ x, const float* __restrict__ W,
    const float* __restrict__ bias, const float* __restrict__ means,
    const float* __restrict__ invcov,
    float* __restrict__ xp, unsigned short* __restrict__ xbf,
    unsigned short* __restrict__ Mbf, float* __restrict__ v2,
    float* __restrict__ cpart)
{
    const int t = threadIdx.x;
    if (blockIdx.x < 512) {
        __shared__ float sv[64][33];
        const int n  = blockIdx.x >> 2;
        const int jq = blockIdx.x & 3;
        const float* Mn = invcov + (size_t)n * (HID_ * HID_) + (size_t)jq * 64 * HID_;
        const float* mu = means + (size_t)n * HID_;
        unsigned short* Mb = Mbf + (size_t)n * (HID_ * HID_) + (size_t)jq * 64 * HID_;
        const int gc = t & 31;           // granule column (k = gc*8..gc*8+7)
        const int r0 = t >> 5;           // 0..7
        const float4 mk0 = *(const float4*)(mu + gc * 8);
        const float4 mk1 = *(const float4*)(mu + gc * 8 + 4);
        #pragma unroll
        for (int i = 0; i < 8; ++i) {
            const int row = r0 + i * 8;  // local row 0..63; (global j)&7 == row&7
            const float* src = Mn + (size_t)row * HID_ + gc * 8;
            const float4 a = *(const float4*)src;
            const float4 b = *(const float4*)(src + 4);
            const int g2 = gc ^ ((row & 7) << 2);
            *(uint4*)(Mb + (size_t)row * HID_ + g2 * 8) =
                make_uint4(pack2(a.x, a.y), pack2(a.z, a.w), pack2(b.x, b.y), pack2(b.z, b.w));
            sv[row][gc] = a.x * mk0.x + a.y * mk0.y + a.z * mk0.z + a.w * mk0.w
                        + b.x * mk1.x + b.y * mk1.y + b.z * mk1.z + b.w * mk1.w;
        }
        __syncthreads();
        if (t < 64) {
            float v = 0.f;
            #pragma unroll
            for (int g = 0; g < 32; ++g) v += sv[t][g];   // row t*33+g -> conflict-free
            const int j = jq * 64 + t;
            v2[(size_t)n * HID_ + j] = 2.f * v;
            float cc = v * mu[j];
            cc += __shfl_xor(cc, 1);
            cc += __shfl_xor(cc, 2);
            cc += __shfl_xor(cc, 4);
            cc += __shfl_xor(cc, 8);
            cc += __shfl_xor(cc, 16);
            cc += __shfl_xor(cc, 32);
            if (t == 0) cpart[n * 4 + jq] = cc;
        }
    } else {
        const int b0 = (blockIdx.x - 512) * 4;
        const int h  = t;                // output col 0..255
        const float bb = bias[h];
        float a0 = bb, a1 = bb, a2 = bb, a3 = bb;
        const float* x0p = x + (size_t)(b0 + 0) * FEAT_;
        const float* x1p = x + (size_t)(b0 + 1) * FEAT_;
        const float* x2p = x + (size_t)(b0 + 2) * FEAT_;
        const float* x3p = x + (size_t)(b0 + 3) * FEAT_;
        #pragma unroll 2
        for (int f = 0; f < FEAT_; f += 4) {
            const float4 xv0 = *(const float4*)(x0p + f);   // block-uniform -> s_load
            const float4 xv1 = *(const float4*)(x1p + f);
            const float4 xv2 = *(const float4*)(x2p + f);
            const float4 xv3 = *(const float4*)(x3p + f);
            const float w0 = W[(size_t)(f + 0) * HID_ + h]; // coalesced, L2/L3-resident
            const float w1 = W[(size_t)(f + 1) * HID_ + h];
            const float w2 = W[(size_t)(f + 2) * HID_ + h];
            const float w3 = W[(size_t)(f + 3) * HID_ + h];
            a0 += xv0.x * w0 + xv0.y * w1 + xv0.z * w2 + xv0.w * w3;
            a1 += xv1.x * w0 + xv1.y * w1 + xv1.z * w2 + xv1.w * w3;
            a2 += xv2.x * w0 + xv2.y * w1 + xv2.z * w2 + xv2.w * w3;
            a3 += xv3.x * w0 + xv3.y * w1 + xv3.z * w2 + xv3.w * w3;
        }
        xp [(size_t)(b0 + 0) * HID_ + h] = a0;
        xp [(size_t)(b0 + 1) * HID_ + h] = a1;
        xp [(size_t)(b0 + 2) * HID_ + h] = a2;
        xp [(size_t)(b0 + 3) * HID_ + h] = a3;
        xbf[(size_t)(b0 + 0) * HID_ + h] = (unsigned short)f2bf(a0);
        xbf[(size_t)(b0 + 1) * HID_ + h] = (unsigned short)f2bf(a1);
        xbf[(size_t)(b0 + 2) * HID_ + h] = (unsigned short)f2bf(a2);
        xbf[(size_t)(b0 + 3) * HID_ + h] = (unsigned short)f2bf(a3);
    }
}

// ---------------- dist: p[jh][b][n] = sum_{j in half} (T[b,j] - v2[n,j]) * xp[b,j] ----------------
// T = x . M_n (bf16 MFMA, fp32 acc). grid (4 bg, 2 jh, 128 n) = 1024 blocks,
// 512 threads, 64 KB LDS -> 2 blocks/CU. M-half staged by pure global_load_lds DMA
// (pre-converted, pre-swizzled bf16) — zero staging VALU. Wave owns 32 b-rows; afrag
// (x rows, bf16, full K) resident in 64 regs; per ct: 8 ds_read_b128 (2-way only) + 16 MFMA.
__global__ __launch_bounds__(512, 4) void dist_kernel(
    const float* __restrict__ xp, const unsigned short* __restrict__ xbf,
    const unsigned short* __restrict__ Mbf, const float* __restrict__ v2,
    float* __restrict__ p)
{
    extern __shared__ unsigned short Ms[];   // 128 rows x 256 el (swizzled) = 65536 B

    const int tid  = threadIdx.x;
    const int bh   = blockIdx.x;       // 0..3
    const int jh   = blockIdx.y;       // 0..1
    const int n    = blockIdx.z;       // 0..127
    const int wave = tid >> 6;
    const int lane = tid & 63;
    const int q    = lane >> 4;        // quad 0..3
    const int l    = lane & 15;

    // ---- DMA stage 64 KB M-half: 64 chunks of 1 KB (wave, iter) ----
    const unsigned short* src = Mbf + (size_t)n * (HID_ * HID_) + (size_t)jh * 32768;
    #pragma unroll
    for (int i = 0; i < 8; ++i) {
        const int c = i * 8 + wave;    // chunk id, wave-uniform
        __builtin_amdgcn_global_load_lds(
            (const __attribute__((address_space(1))) unsigned int*)(src + (size_t)c * 512 + lane * 8),
            (__attribute__((address_space(3))) unsigned int*)&Ms[c * 512],
            16, 0, 0);
    }

    // ---- afrag: x rows (bf16, pre-converted), full K, 2 row-blocks of 16 ----
    // A layout: A[m=lane&15][k=quad*8+j]
    bf16x8 afrag[2][8];
    #pragma unroll
    for (int rb = 0; rb < 2; ++rb) {
        const unsigned short* xr = xbf + (size_t)(bh * 256 + wave * 32 + rb * 16 + l) * HID_;
        #pragma unroll
        for (int kk = 0; kk < 8; ++kk)
            afrag[rb][kk] = *(const bf16x8*)(xr + kk * 32 + q * 8);
    }
    // v2 per lane per ct (j = jh*128 + ct*16 + l)
    float v2l[8];
    #pragma unroll
    for (int ct = 0; ct < 8; ++ct)
        v2l[ct] = v2[(size_t)n * HID_ + jh * 128 + ct * 16 + l];

    __syncthreads();   // drains the DMA (vmcnt) + the only barrier

    float part[8];
    #pragma unroll
    for (int i = 0; i < 8; ++i) part[i] = 0.f;

    // epilogue x source: row (bh*256 + wave*32 + q*4 + r + rb*16), col (jh*128 + ct*16 + l)
    const size_t xbase = (size_t)(bh * 256 + wave * 32 + q * 4) * HID_ + jh * 128 + l;

    #pragma unroll
    for (int ct = 0; ct < 8; ++ct) {
        // hoist fp32 x loads for the fused epilogue
        float xl[8];
        #pragma unroll
        for (int rb = 0; rb < 2; ++rb)
            #pragma unroll
            for (int r = 0; r < 4; ++r)
                xl[rb * 4 + r] = xp[xbase + (size_t)(rb * 16 + r) * HID_ + ct * 16];

        f32x4 acc0 = {0.f,0.f,0.f,0.f}, acc1 = {0.f,0.f,0.f,0.f};
        #pragma unroll
        for (int kk = 0; kk < 8; ++kk) {
            // swizzled read: row jr=ct*16+l, granule (kk*4+q)^((l&7)<<2)  -> 2-way banks (free)
            const bf16x8 bfrag = *(const bf16x8*)&Ms[(ct * 16 + l) * HID_ +
                                                     (((kk * 4 + q) ^ ((l & 7) << 2)) << 3)];
            acc0 = __builtin_amdgcn_mfma_f32_16x16x32_bf16(afrag[0][kk], bfrag, acc0, 0, 0, 0);
            acc1 = __builtin_amdgcn_mfma_f32_16x16x32_bf16(afrag[1][kk], bfrag, acc1, 0, 0, 0);
        }
        // fused epilogue: part += (T - v2) * x   (C/D layout: col=lane&15, row=quad*4+reg)
        const float vv = v2l[ct];
        #pragma unroll
        for (int r = 0; r < 4; ++r) {
            part[r]     += (acc0[r] - vv) * xl[r];
            part[4 + r] += (acc1[r] - vv) * xl[4 + r];
        }
    }

    // reduce across the 16 col-lanes of each quad
    #pragma unroll
    for (int i = 0; i < 8; ++i) {
        float v = part[i];
        v += __shfl_xor(v, 1);
        v += __shfl_xor(v, 2);
        v += __shfl_xor(v, 4);
        v += __shfl_xor(v, 8);
        part[i] = v;
    }
    if (l == 0) {
        float* pb = p + (size_t)jh * (B_ * N_);
        #pragma unroll
        for (int i = 0; i < 8; ++i) {
            const int row = bh * 256 + wave * 32 + (i >> 2) * 16 + q * 4 + (i & 3);
            pb[(size_t)row * N_ + n] = part[i];
        }
    }
}

// ---------------- finalize: distmat = sqrt(p0 + p1 + c[n] + 1e-12) ----------------
__global__ __launch_bounds__(256) void finalize_kernel(
    const float* __restrict__ p, const float* __restrict__ cpart,
    float* __restrict__ out)
{
    const int i = blockIdx.x * 256 + threadIdx.x;   // 0..131071
    const int n = i & (N_ - 1);
    const float c = cpart[n * 4] + cpart[n * 4 + 1] + cpart[n * 4 + 2] + cpart[n * 4 + 3];
    out[1 + i] = sqrtf(p[i] + p[B_ * N_ + i] + c + 1e-12f);
}

// ---------------- loss: sum_b distmat[b, labels[b]] / B + clip residue ----------------
__global__ __launch_bounds__(1024) void loss_kernel(
    const float* __restrict__ distmat, const int* __restrict__ labels,
    float* __restrict__ out)
{
    __shared__ float red[16];
    const int b = threadIdx.x;                 // 1024 threads = one per batch row
    float s = distmat[(size_t)b * N_ + labels[b]];
    #pragma unroll
    for (int m = 1; m <= 32; m <<= 1) s += __shfl_xor(s, m);
    if ((b & 63) == 0) red[b >> 6] = s;
    __syncthreads();
    if (b == 0) {
        float t = 0.f;
        #pragma unroll
        for (int i = 0; i < 16; ++i) t += red[i];
        // masked-out entries clip to 1e-12: B*(N-1) of them, /B -> (N-1)*1e-12
        out[0] = t / (float)B_ + (float)(N_ - 1) * 1e-12f;
    }
}

extern "C" void kernel_launch(void* const* d_in, const int* in_sizes, int n_in,
                              void* d_out, int out_size, void* d_ws, size_t ws_size,
                              hipStream_t stream) {
    const float* x      = (const float*)d_in[0];
    const int*   labels = (const int*)d_in[1];
    const float* W      = (const float*)d_in[2];
    const float* bias   = (const float*)d_in[3];
    const float* means  = (const float*)d_in[4];
    const float* invcov = (const float*)d_in[5];
    float* out = (float*)d_out;

    // workspace carve-up (~19.5 MB total)
    char* ws = (char*)d_ws;
    unsigned short* Mbf   = (unsigned short*)(ws);               // 16,777,216 B
    float*          xp    = (float*)         (ws + 16777216);    //  1,048,576 B
    unsigned short* xbf   = (unsigned short*)(ws + 17825792);    //    524,288 B
    float*          v2    = (float*)         (ws + 18350080);    //    131,072 B
    float*          cpart = (float*)         (ws + 18481152);    //      2,048 B
    float*          p     = (float*)         (ws + 18483200);    //  1,048,576 B

    constexpr int DIST_LDS = 128 * HID_ * 2;   // 65536 B dynamic LDS
    (void)hipFuncSetAttribute((const void*)dist_kernel,
                              hipFuncAttributeMaxDynamicSharedMemorySize, DIST_LDS);

    prep_kernel<<<dim3(768), 256, 0, stream>>>(x, W, bias, means, invcov,
                                               xp, xbf, Mbf, v2, cpart);
    dist_kernel<<<dim3(4, 2, N_), 512, DIST_LDS, stream>>>(xp, xbf, Mbf, v2, p);
    finalize_kernel<<<dim3((B_ * N_) / 256), 256, 0, stream>>>(p, cpart, out);
    loss_kernel<<<1, 1024, 0, stream>>>(out + 1, labels, out);
}

// Round 6
// 146.514 us; speedup vs baseline: 1.4184x; 1.0092x over previous
//
#include <hip/hip_runtime.h>
#include <hip/hip_bf16.h>

#define B_    1024
#define N_    128
#define FEAT_ 512
#define HID_  256

typedef __bf16 bf16x8 __attribute__((ext_vector_type(8)));
typedef float  f32x4  __attribute__((ext_vector_type(4)));

__device__ __forceinline__ unsigned int f2bf(float f) {
    unsigned int u = __float_as_uint(f);
    u += 0x7fffu + ((u >> 16) & 1u);   // round-to-nearest-even
    return u >> 16;
}
__device__ __forceinline__ unsigned int pack2(float a, float b) {
    return f2bf(a) | (f2bf(b) << 16);
}

// ---------------- prep: proj (blocks 0..255) + conv (blocks 256..2303) ----------------
// proj: 4 b-rows/block; x rows staged in LDS (kills s_load latency chain); W loads
//   unrolled 8-deep; writes xp fp32 + xbf bf16.
// conv: block=(n, 16-row group jg). Thread owns 2 granules: 32B contiguous fp32 load ->
//   uint4 store at swizzled granule  elem(j,k) -> j*256 + ((k>>3)^((j&7)<<2))*8 + (k&7).
//   2048 blocks (~8/CU) -> latency hidden by TLP, not ILP. v2[j]=2*sum_k mu_k M[j,k]
//   via LDS sv[16][33] + shuffles; cpart[n*16+jg] = sum_j(mu_j * (Mmu)_j) block partial.
__global__ __launch_bounds__(256) void prep_kernel(
    const float* __restrict__ x, const float* __restrict__ W,
    const float* __restrict__ bias, const float* __restrict__ means,
    const float* __restrict__ invcov,
    float* __restrict__ xp, unsigned short* __restrict__ xbf,
    unsigned short* __restrict__ Mbf, float* __restrict__ v2,
    float* __restrict__ cpart)
{
    const int t = threadIdx.x;
    if (blockIdx.x < 256) {
        // ---------------- proj role ----------------
        __shared__ float xs[4][FEAT_];          // 8 KB
        const int b0 = blockIdx.x * 4;
        {
            const float4* xsrc = (const float4*)(x + (size_t)b0 * FEAT_);  // 512 float4
            const float4 v0 = xsrc[t];
            const float4 v1 = xsrc[t + 256];
            ((float4*)&xs[0][0])[t]       = v0;
            ((float4*)&xs[0][0])[t + 256] = v1;
        }
        __syncthreads();
        const int h = t;                        // output col 0..255
        const float bb = bias[h];
        float a0 = bb, a1 = bb, a2 = bb, a3 = bb;
        #pragma unroll 8
        for (int f = 0; f < FEAT_; ++f) {
            const float w = W[(size_t)f * HID_ + h];   // coalesced, L2-resident
            a0 += xs[0][f] * w;                        // LDS broadcast reads
            a1 += xs[1][f] * w;
            a2 += xs[2][f] * w;
            a3 += xs[3][f] * w;
        }
        xp [(size_t)(b0 + 0) * HID_ + h] = a0;
        xp [(size_t)(b0 + 1) * HID_ + h] = a1;
        xp [(size_t)(b0 + 2) * HID_ + h] = a2;
        xp [(size_t)(b0 + 3) * HID_ + h] = a3;
        xbf[(size_t)(b0 + 0) * HID_ + h] = (unsigned short)f2bf(a0);
        xbf[(size_t)(b0 + 1) * HID_ + h] = (unsigned short)f2bf(a1);
        xbf[(size_t)(b0 + 2) * HID_ + h] = (unsigned short)f2bf(a2);
        xbf[(size_t)(b0 + 3) * HID_ + h] = (unsigned short)f2bf(a3);
    } else {
        // ---------------- conv role ----------------
        __shared__ float sv[16][33];
        __shared__ float sw[2];
        const int cb = blockIdx.x - 256;   // 0..2047
        const int n  = cb >> 4;            // 0..127
        const int jg = cb & 15;            // 16-row group
        const float* Mn = invcov + (size_t)n * (HID_ * HID_) + (size_t)jg * 16 * HID_;
        const float* mu = means + (size_t)n * HID_;
        unsigned short* Mb = Mbf + (size_t)n * (HID_ * HID_) + (size_t)jg * 16 * HID_;
        const int gc = t & 31;             // granule column (k = gc*8 .. gc*8+7)
        const int r0 = t >> 5;             // 0..7 -> rows r0 and r0+8
        const float4 mk0 = *(const float4*)(mu + gc * 8);
        const float4 mk1 = *(const float4*)(mu + gc * 8 + 4);
        #pragma unroll
        for (int i = 0; i < 2; ++i) {
            const int row = r0 + i * 8;    // local 0..15; global j = jg*16+row, j&7 == row&7
            const float* src = Mn + (size_t)row * HID_ + gc * 8;
            const float4 a = *(const float4*)src;
            const float4 b = *(const float4*)(src + 4);
            const int g2 = gc ^ ((row & 7) << 2);
            *(uint4*)(Mb + (size_t)row * HID_ + g2 * 8) =
                make_uint4(pack2(a.x, a.y), pack2(a.z, a.w), pack2(b.x, b.y), pack2(b.z, b.w));
            sv[row][gc] = a.x * mk0.x + a.y * mk0.y + a.z * mk0.z + a.w * mk0.w
                        + b.x * mk1.x + b.y * mk1.y + b.z * mk1.z + b.w * mk1.w;
        }
        __syncthreads();
        if (t < 128) {
            const int row = t >> 3;        // 0..15 (8 per wave)
            const int i0  = (t & 7) * 4;
            float v = sv[row][i0] + sv[row][i0 + 1] + sv[row][i0 + 2] + sv[row][i0 + 3];
            v += __shfl_xor(v, 1);         // reduce across the 8 gc-groups (lane bits 0..2)
            v += __shfl_xor(v, 2);
            v += __shfl_xor(v, 4);
            const int j = jg * 16 + row;
            if ((t & 7) == 0) v2[(size_t)n * HID_ + j] = 2.f * v;
            float cc = ((t & 7) == 0) ? v * mu[j] : 0.f;
            cc += __shfl_xor(cc, 8);       // sum the 8 rows of this wave
            cc += __shfl_xor(cc, 16);
            cc += __shfl_xor(cc, 32);
            if ((t & 63) == 0) sw[t >> 6] = cc;
        }
        __syncthreads();
        if (t == 0) cpart[cb] = sw[0] + sw[1];
    }
}

// ---------------- dist: p[jh][b][n] = sum_{j in half} (T[b,j] - v2[n,j]) * xp[b,j] ----------------
// T = x . M_n (bf16 MFMA, fp32 acc). grid (4 bg, 2 jh, 128 n) = 1024 blocks,
// 512 threads, 64 KB LDS -> 2 blocks/CU. M-half staged by pure global_load_lds DMA
// (pre-converted, pre-swizzled bf16) — zero staging VALU. Wave owns 32 b-rows; afrag
// (x rows, bf16, full K) resident in 64 regs; per ct: 8 ds_read_b128 (2-way only) + 16 MFMA.
__global__ __launch_bounds__(512, 4) void dist_kernel(
    const float* __restrict__ xp, const unsigned short* __restrict__ xbf,
    const unsigned short* __restrict__ Mbf, const float* __restrict__ v2,
    float* __restrict__ p)
{
    extern __shared__ unsigned short Ms[];   // 128 rows x 256 el (swizzled) = 65536 B

    const int tid  = threadIdx.x;
    const int bh   = blockIdx.x;       // 0..3
    const int jh   = blockIdx.y;       // 0..1
    const int n    = blockIdx.z;       // 0..127
    const int wave = tid >> 6;
    const int lane = tid & 63;
    const int q    = lane >> 4;        // quad 0..3
    const int l    = lane & 15;

    // ---- DMA stage 64 KB M-half: 64 chunks of 1 KB (wave, iter) ----
    const unsigned short* src = Mbf + (size_t)n * (HID_ * HID_) + (size_t)jh * 32768;
    #pragma unroll
    for (int i = 0; i < 8; ++i) {
        const int c = i * 8 + wave;    // chunk id, wave-uniform
        __builtin_amdgcn_global_load_lds(
            (const __attribute__((address_space(1))) unsigned int*)(src + (size_t)c * 512 + lane * 8),
            (__attribute__((address_space(3))) unsigned int*)&Ms[c * 512],
            16, 0, 0);
    }

    // ---- afrag: x rows (bf16, pre-converted), full K, 2 row-blocks of 16 ----
    // A layout: A[m=lane&15][k=quad*8+j]
    bf16x8 afrag[2][8];
    #pragma unroll
    for (int rb = 0; rb < 2; ++rb) {
        const unsigned short* xr = xbf + (size_t)(bh * 256 + wave * 32 + rb * 16 + l) * HID_;
        #pragma unroll
        for (int kk = 0; kk < 8; ++kk)
            afrag[rb][kk] = *(const bf16x8*)(xr + kk * 32 + q * 8);
    }
    // v2 per lane per ct (j = jh*128 + ct*16 + l)
    float v2l[8];
    #pragma unroll
    for (int ct = 0; ct < 8; ++ct)
        v2l[ct] = v2[(size_t)n * HID_ + jh * 128 + ct * 16 + l];

    __syncthreads();   // drains the DMA (vmcnt) + the only barrier

    float part[8];
    #pragma unroll
    for (int i = 0; i < 8; ++i) part[i] = 0.f;

    // epilogue x source: row (bh*256 + wave*32 + q*4 + r + rb*16), col (jh*128 + ct*16 + l)
    const size_t xbase = (size_t)(bh * 256 + wave * 32 + q * 4) * HID_ + jh * 128 + l;

    #pragma unroll
    for (int ct = 0; ct < 8; ++ct) {
        // hoist fp32 x loads for the fused epilogue
        float xl[8];
        #pragma unroll
        for (int rb = 0; rb < 2; ++rb)
            #pragma unroll
            for (int r = 0; r < 4; ++r)
                xl[rb * 4 + r] = xp[xbase + (size_t)(rb * 16 + r) * HID_ + ct * 16];

        f32x4 acc0 = {0.f,0.f,0.f,0.f}, acc1 = {0.f,0.f,0.f,0.f};
        #pragma unroll
        for (int kk = 0; kk < 8; ++kk) {
            // swizzled read: row jr=ct*16+l, granule (kk*4+q)^((l&7)<<2)  -> 2-way banks (free)
            const bf16x8 bfrag = *(const bf16x8*)&Ms[(ct * 16 + l) * HID_ +
                                                     (((kk * 4 + q) ^ ((l & 7) << 2)) << 3)];
            acc0 = __builtin_amdgcn_mfma_f32_16x16x32_bf16(afrag[0][kk], bfrag, acc0, 0, 0, 0);
            acc1 = __builtin_amdgcn_mfma_f32_16x16x32_bf16(afrag[1][kk], bfrag, acc1, 0, 0, 0);
        }
        // fused epilogue: part += (T - v2) * x   (C/D layout: col=lane&15, row=quad*4+reg)
        const float vv = v2l[ct];
        #pragma unroll
        for (int r = 0; r < 4; ++r) {
            part[r]     += (acc0[r] - vv) * xl[r];
            part[4 + r] += (acc1[r] - vv) * xl[4 + r];
        }
    }

    // reduce across the 16 col-lanes of each quad
    #pragma unroll
    for (int i = 0; i < 8; ++i) {
        float v = part[i];
        v += __shfl_xor(v, 1);
        v += __shfl_xor(v, 2);
        v += __shfl_xor(v, 4);
        v += __shfl_xor(v, 8);
        part[i] = v;
    }
    if (l == 0) {
        float* pb = p + (size_t)jh * (B_ * N_);
        #pragma unroll
        for (int i = 0; i < 8; ++i) {
            const int row = bh * 256 + wave * 32 + (i >> 2) * 16 + q * 4 + (i & 3);
            pb[(size_t)row * N_ + n] = part[i];
        }
    }
}

// ---------------- finalize: distmat = sqrt(p0 + p1 + c[n] + 1e-12) ----------------
__global__ __launch_bounds__(256) void finalize_kernel(
    const float* __restrict__ p, const float* __restrict__ cpart,
    float* __restrict__ out)
{
    __shared__ float sc[128];
    const int t = threadIdx.x;
    if (t < 128) {
        float s = 0.f;
        #pragma unroll
        for (int g = 0; g < 16; ++g) s += cpart[t * 16 + g];
        sc[t] = s;
    }
    __syncthreads();
    const int i = blockIdx.x * 256 + t;             // 0..131071
    const int n = i & (N_ - 1);
    out[1 + i] = sqrtf(p[i] + p[B_ * N_ + i] + sc[n] + 1e-12f);
}

// ---------------- loss: sum_b distmat[b, labels[b]] / B + clip residue ----------------
__global__ __launch_bounds__(1024) void loss_kernel(
    const float* __restrict__ distmat, const int* __restrict__ labels,
    float* __restrict__ out)
{
    __shared__ float red[16];
    const int b = threadIdx.x;                 // 1024 threads = one per batch row
    float s = distmat[(size_t)b * N_ + labels[b]];
    #pragma unroll
    for (int m = 1; m <= 32; m <<= 1) s += __shfl_xor(s, m);
    if ((b & 63) == 0) red[b >> 6] = s;
    __syncthreads();
    if (b == 0) {
        float t = 0.f;
        #pragma unroll
        for (int i = 0; i < 16; ++i) t += red[i];
        // masked-out entries clip to 1e-12: B*(N-1) of them, /B -> (N-1)*1e-12
        out[0] = t / (float)B_ + (float)(N_ - 1) * 1e-12f;
    }
}

extern "C" void kernel_launch(void* const* d_in, const int* in_sizes, int n_in,
                              void* d_out, int out_size, void* d_ws, size_t ws_size,
                              hipStream_t stream) {
    const float* x      = (const float*)d_in[0];
    const int*   labels = (const int*)d_in[1];
    const float* W      = (const float*)d_in[2];
    const float* bias   = (const float*)d_in[3];
    const float* means  = (const float*)d_in[4];
    const float* invcov = (const float*)d_in[5];
    float* out = (float*)d_out;

    // workspace carve-up (~19.5 MB total)
    char* ws = (char*)d_ws;
    unsigned short* Mbf   = (unsigned short*)(ws);               // 16,777,216 B
    float*          xp    = (float*)         (ws + 16777216);    //  1,048,576 B
    unsigned short* xbf   = (unsigned short*)(ws + 17825792);    //    524,288 B
    float*          v2    = (float*)         (ws + 18350080);    //    131,072 B
    float*          cpart = (float*)         (ws + 18481152);    //      8,192 B
    float*          p     = (float*)         (ws + 18489344);    //  1,048,576 B

    constexpr int DIST_LDS = 128 * HID_ * 2;   // 65536 B dynamic LDS
    (void)hipFuncSetAttribute((const void*)dist_kernel,
                              hipFuncAttributeMaxDynamicSharedMemorySize, DIST_LDS);

    prep_kernel<<<dim3(2304), 256, 0, stream>>>(x, W, bias, means, invcov,
                                                xp, xbf, Mbf, v2, cpart);
    dist_kernel<<<dim3(4, 2, N_), 512, DIST_LDS, stream>>>(xp, xbf, Mbf, v2, p);
    finalize_kernel<<<dim3((B_ * N_) / 256), 256, 0, stream>>>(p, cpart, out);
    loss_kernel<<<1, 1024, 0, stream>>>(out + 1, labels, out);
}